// Round 2
// baseline (461.223 us; speedup 1.0000x reference)
//
#include <hip/hip_runtime.h>
#include <hip/hip_bf16.h>

// CustomTransformerBlock: B=4,S=2048,D=1024,H=16,DH=64,W=1024,DFF=4096
#define BB 4
#define SS 2048
#define DD 1024
#define HH 16
#define DHH 64
#define WW 1024
#define DFF 4096
#define MM (BB*SS)
#define NEGV (-1e10f)

using f32x4 = __attribute__((ext_vector_type(4))) float;
using s16x8 = __attribute__((ext_vector_type(8))) short;
using s16x4 = __attribute__((ext_vector_type(4))) short;
using u64 = unsigned long long;

typedef const __attribute__((address_space(1))) void* gas_t;
typedef __attribute__((address_space(3))) void* las_t;

__device__ inline short f2b(float f) {
  __hip_bfloat16 h = __float2bfloat16(f);
  return __builtin_bit_cast(short, h);
}
__device__ inline float b2f(short u) {
  __hip_bfloat16 h = __builtin_bit_cast(__hip_bfloat16, u);
  return __bfloat162float(h);
}

// 16B global->LDS direct. LDS dest is wave-uniform base + lane*16 (HW rule).
__device__ inline void gload_lds16(const short* g, short* lds) {
  __builtin_amdgcn_global_load_lds((gas_t)g, (las_t)lds, 16, 0, 0);
}

__device__ inline f32x4 mfma16(s16x8 a, s16x8 b, f32x4 c) {
  return __builtin_amdgcn_mfma_f32_16x16x32_bf16(a, b, c, 0, 0, 0);
}

// -------------------- LayerNorm (row of 1024), out bf16 --------------------
template<int IN_BF16>
__global__ __launch_bounds__(256) void ln_kernel(const void* __restrict__ inp,
                                                 const float* __restrict__ g,
                                                 const float* __restrict__ bta,
                                                 short* __restrict__ outp) {
  int row = blockIdx.x;
  int t = threadIdx.x;
  float v[4];
  if constexpr (IN_BF16) {
    s16x4 r4 = *((const s16x4*)((const short*)inp + (size_t)row*DD) + t);
    v[0]=b2f(r4[0]); v[1]=b2f(r4[1]); v[2]=b2f(r4[2]); v[3]=b2f(r4[3]);
  } else {
    f32x4 r4 = *((const f32x4*)((const float*)inp + (size_t)row*DD) + t);
    v[0]=r4[0]; v[1]=r4[1]; v[2]=r4[2]; v[3]=r4[3];
  }
  float s = v[0]+v[1]+v[2]+v[3];
  float sq = v[0]*v[0]+v[1]*v[1]+v[2]*v[2]+v[3]*v[3];
  for (int m=1;m<64;m<<=1){ s += __shfl_xor(s,m); sq += __shfl_xor(sq,m); }
  __shared__ float red[8];
  int wv = t>>6;
  if ((t&63)==0){ red[wv]=s; red[4+wv]=sq; }
  __syncthreads();
  s  = red[0]+red[1]+red[2]+red[3];
  sq = red[4]+red[5]+red[6]+red[7];
  float mean = s*(1.f/DD);
  float rstd = rsqrtf(sq*(1.f/DD) - mean*mean + 1e-5f);
  int col = t*4;
  s16x4 o;
  #pragma unroll
  for (int j=0;j<4;++j) o[j] = f2b((v[j]-mean)*rstd*g[col+j]+bta[col+j]);
  *((s16x4*)(outp + (size_t)row*DD) + t) = o;
}

// ------------- fp32 [K][N] -> bf16 [N][K] transpose-cast (weights) ----------
__global__ __launch_bounds__(256) void transpose_cast(const float* __restrict__ in,
                                                      short* __restrict__ out,
                                                      int K, int N) {
  __shared__ float tile[32][33];
  int n0 = blockIdx.x*32, k0 = blockIdx.y*32;
  int tx = threadIdx.x & 31, ty = threadIdx.x >> 5;
  #pragma unroll
  for (int j=0;j<4;++j) tile[ty+8*j][tx] = in[(size_t)(k0+ty+8*j)*N + n0+tx];
  __syncthreads();
  #pragma unroll
  for (int j=0;j<4;++j) out[(size_t)(n0+ty+8*j)*K + k0+tx] = f2b(tile[tx][ty+8*j]);
}

// ---- pad bool(int) -> per-(b,col16) u64 bitmask: bit(c*4+nf) = pad[c*64+nf*16+col16]
__global__ void pad_bitmask(const int* __restrict__ pad, u64* __restrict__ pm) {
  int idx = threadIdx.x;            // 64 threads: b(2b) x col16(4b)
  int b_ = idx>>4, col = idx&15;
  const int* pb = pad + b_*SS + (SS-WW);
  u64 m = 0;
  for (int c=0;c<16;++c)
    for (int nf=0;nf<4;++nf)
      if (pb[c*64+nf*16+col]) m |= (1ull << (c*4+nf));
  pm[idx] = m;
}

// -------------------- GEMM: C = A[M,K] * Bt[N,K]^T + bias --------------------
// 128x128 tile, BK=32, 256 thr = 4 waves (2x2), each wave 64x64 via 4x4 16x16x32.
// EPI: 0=q(bf16 out), 1=kv(split k/v panels), 2=ff1(silu,bf16), 3=ff2(+x, f32 out)
template<int EPI>
__global__ __launch_bounds__(256) void gemm_bt(const short* __restrict__ A,
                                               const short* __restrict__ Bt,
                                               const float* __restrict__ bias,
                                               void* __restrict__ out1,
                                               void* __restrict__ out2,
                                               const float* __restrict__ resid,
                                               int N, int K) {
  __shared__ short As[128*32], Bs[128*32];
  int tid = threadIdx.x, l = tid&63;
  int wv = tid>>6, wm = wv>>1, wn = wv&1;
  int bx = blockIdx.x, by = blockIdx.y;
  const short* Ablk;
  if constexpr (EPI==1) {
    int b_ = (by*128)>>10;          // batch
    int w0 = (by*128)&1023;         // window row
    Ablk = A + ((size_t)b_*SS + (SS-WW) + w0)*DD;
  } else {
    Ablk = A + (size_t)by*128*K;
  }
  const short* Bblk = Bt + (size_t)bx*128*K;
  f32x4 acc[4][4];
  #pragma unroll
  for (int i=0;i<4;++i)
    #pragma unroll
    for(int j=0;j<4;++j)
      #pragma unroll
      for(int r=0;r<4;++r) acc[i][j][r]=0.f;
  int rA = l & 15;
  int cslot = (((l>>4) ^ ((l>>1)&3))*8);
  for (int kt=0; kt<K; kt+=32) {
    __syncthreads();
    #pragma unroll
    for (int p=0;p<2;++p) {
      int s = p*256 + tid;
      int srow = s>>2;
      int scs = (((s&3) ^ ((s>>3)&3))*8);   // pre-swizzled source slot
      gload_lds16(Ablk + (size_t)srow*K + kt + scs, &As[(p*256 + (tid & ~63))*8]);
      gload_lds16(Bblk + (size_t)srow*K + kt + scs, &Bs[(p*256 + (tid & ~63))*8]);
    }
    __syncthreads();
    s16x8 af[4], bfr[4];
    #pragma unroll
    for (int mf=0;mf<4;++mf) af[mf]  = *(const s16x8*)&As[(wm*64+mf*16+rA)*32 + cslot];
    #pragma unroll
    for (int nf=0;nf<4;++nf) bfr[nf] = *(const s16x8*)&Bs[(wn*64+nf*16+rA)*32 + cslot];
    #pragma unroll
    for (int mf=0;mf<4;++mf)
      #pragma unroll
      for (int nf=0;nf<4;++nf)
        acc[mf][nf] = mfma16(af[mf], bfr[nf], acc[mf][nf]);
  }
  #pragma unroll
  for (int mf=0;mf<4;++mf) {
    #pragma unroll
    for (int nf=0;nf<4;++nf) {
      #pragma unroll
      for (int r=0;r<4;++r) {
        int row = by*128 + wm*64 + mf*16 + ((l>>4)<<2) + r;  // C row=(l>>4)*4+r
        int col = bx*128 + wn*64 + nf*16 + (l&15);           // C col=l&15
        float v = acc[mf][nf][r] + bias[col];
        if constexpr (EPI==0) {
          ((short*)out1)[(size_t)row*N + col] = f2b(v);
        } else if constexpr (EPI==1) {
          int b_ = row>>10, w_ = row&1023;
          if (col < DD) {        // K head: [b][h][w][dh]
            int h = col>>6, dh = col&63;
            ((short*)out1)[(((size_t)(b_*HH+h))*WW + w_)*DHH + dh] = f2b(v);
          } else {               // V head transposed: [b][h][dh][w]
            int cc = col - DD;
            int h = cc>>6, dh = cc&63;
            ((short*)out2)[(((size_t)(b_*HH+h))*DHH + dh)*WW + w_] = f2b(v);
          }
        } else if constexpr (EPI==2) {
          float sv = v / (1.f + __expf(-v));   // silu
          ((short*)out1)[(size_t)row*N + col] = f2b(sv);
        } else {
          ((float*)out1)[(size_t)row*N + col] = v + resid[(size_t)row*N + col];
        }
      }
    }
  }
}

// -------------------- Flash attention over W=1024 keys --------------------
// grid (16, H, B); 4 waves x 32 q-rows = 128 q-rows/block; 64-key chunks,
// double-buffered K/V staging (1 barrier/chunk), pad via u64 bitmask.
__global__ __launch_bounds__(256) void attn_kernel(const short* __restrict__ q,
    const short* __restrict__ kpan, const short* __restrict__ vtpan,
    const u64* __restrict__ pmarr, short* __restrict__ outp) {
  __shared__ short Ks[2][64*64], Vts[2][64*64];
  __shared__ short P[4][32*72];   // wave-private P, 32 rows x 72 shorts
  int tid = threadIdx.x, l = tid&63, wv = tid>>6;
  int t = 15 - blockIdx.x;        // heavy blocks (more chunks) first
  int h = blockIdx.y, bb = blockIdx.z;
  int s0 = t*128;
  int r0 = s0 + wv*32;
  const short* kbase = kpan + (size_t)(bb*HH+h)*WW*DHH;
  const short* vbase = vtpan + (size_t)(bb*HH+h)*DHH*WW;
  u64 pmask = pmarr[bb*16 + (l&15)];
  s16x8 aq[2][2];
  #pragma unroll
  for (int g=0;g<2;++g)
    #pragma unroll
    for (int kf=0;kf<2;++kf)
      aq[g][kf] = *(const s16x8*)(q + ((size_t)bb*SS + r0 + g*16 + (l&15))*DD
                                    + h*DHH + (l>>4)*8 + kf*32);
  f32x4 oacc[2][4];
  float mrun[2][4], lrun[2][4];
  #pragma unroll
  for (int g=0;g<2;++g)
    #pragma unroll
    for (int i=0;i<4;++i) {
      #pragma unroll
      for (int r=0;r<4;++r) oacc[g][i][r]=0.f;
      mrun[g][i]=-INFINITY; lrun[g][i]=0.f;
    }
  int nch = 2*t+2 < 16 ? 2*t+2 : 16;

  auto stage = [&](int c, int bi) {
    #pragma unroll
    for (int p=0;p<2;++p) {
      int s = p*256 + tid;
      int row = s>>3;
      int scs = (((s&7) ^ (row&7))*8);
      gload_lds16(kbase + (size_t)(c*64+row)*DHH + scs, &Ks[bi][(p*256 + (tid&~63))*8]);
      gload_lds16(vbase + (size_t)row*WW + c*64 + scs,  &Vts[bi][(p*256 + (tid&~63))*8]);
    }
  };

  auto compute = [&](int c, int bi) {
    // ---- QK^T: 32 q-rows x 64 keys ----
    f32x4 sc[2][4];
    #pragma unroll
    for (int g=0;g<2;++g)
      #pragma unroll
      for (int nf=0;nf<4;++nf)
        #pragma unroll
        for (int r=0;r<4;++r) sc[g][nf][r]=0.f;
    __builtin_amdgcn_s_setprio(1);
    #pragma unroll
    for (int nf=0;nf<4;++nf) {
      int row = nf*16 + (l&15);
      s16x8 bk0 = *(const s16x8*)&Ks[bi][row*64 + ((((l>>4)    ) ^ (l&7))*8)];
      s16x8 bk1 = *(const s16x8*)&Ks[bi][row*64 + (((4 + (l>>4)) ^ (l&7))*8)];
      #pragma unroll
      for (int g=0;g<2;++g) {
        sc[g][nf] = mfma16(aq[g][0], bk0, sc[g][nf]);
        sc[g][nf] = mfma16(aq[g][1], bk1, sc[g][nf]);
      }
    }
    __builtin_amdgcn_s_setprio(0);
    // ---- mask + online softmax (rows in 16-lane groups) ----
    int diag = (c >= 2*t);   // only diagonal chunks need the causal compare
    float pm[2][4];
    #pragma unroll
    for (int g=0;g<2;++g)
      #pragma unroll
      for (int r=0;r<4;++r) pm[g][r] = -INFINITY;
    #pragma unroll
    for (int nf=0;nf<4;++nf) {
      int j = c*64 + nf*16 + (l&15);
      int padj = (int)((pmask >> (c*4+nf)) & 1ull);
      #pragma unroll
      for (int g=0;g<2;++g)
        #pragma unroll
        for (int r=0;r<4;++r) {
          float xv = padj ? NEGV : sc[g][nf][r]*0.03125f;   // 1/sqrt(1024)
          if (diag) {
            int sq_ = r0 + g*16 + ((l>>4)<<2) + r;
            xv = (j > sq_) ? NEGV : xv;
          }
          sc[g][nf][r] = xv;
          pm[g][r] = fmaxf(pm[g][r], xv);
        }
    }
    #pragma unroll
    for (int m=1;m<16;m<<=1)
      #pragma unroll
      for (int g=0;g<2;++g)
        #pragma unroll
        for (int r=0;r<4;++r) pm[g][r] = fmaxf(pm[g][r], __shfl_xor(pm[g][r], m));
    float scale[2][4], ls[2][4];
    #pragma unroll
    for (int g=0;g<2;++g)
      #pragma unroll
      for (int r=0;r<4;++r) {
        float mn = fmaxf(mrun[g][r], pm[g][r]);
        scale[g][r] = __expf(mrun[g][r]-mn);
        mrun[g][r] = mn;
        ls[g][r] = 0.f;
      }
    #pragma unroll
    for (int nf=0;nf<4;++nf)
      #pragma unroll
      for (int g=0;g<2;++g)
        #pragma unroll
        for (int r=0;r<4;++r) {
          float p_ = __expf(sc[g][nf][r]-mrun[g][r]);
          sc[g][nf][r]=p_; ls[g][r]+=p_;
        }
    #pragma unroll
    for (int m=1;m<16;m<<=1)
      #pragma unroll
      for (int g=0;g<2;++g)
        #pragma unroll
        for (int r=0;r<4;++r) ls[g][r] += __shfl_xor(ls[g][r], m);
    #pragma unroll
    for (int g=0;g<2;++g)
      #pragma unroll
      for (int r=0;r<4;++r) lrun[g][r] = lrun[g][r]*scale[g][r] + ls[g][r];
    #pragma unroll
    for (int g=0;g<2;++g)
      #pragma unroll
      for (int nf=0;nf<4;++nf)
        #pragma unroll
        for (int r=0;r<4;++r) oacc[g][nf][r] *= scale[g][r];
    // ---- P -> wave-private LDS (bf16), then PV MFMA ----
    short* Pw = &P[wv][0];
    #pragma unroll
    for (int g=0;g<2;++g)
      #pragma unroll
      for (int nf=0;nf<4;++nf)
        #pragma unroll
        for (int r=0;r<4;++r)
          Pw[(g*16+((l>>4)<<2)+r)*72 + nf*16 + (l&15)] = f2b(sc[g][nf][r]);
    __builtin_amdgcn_s_setprio(1);
    #pragma unroll
    for (int ks=0;ks<2;++ks) {
      s16x8 ap[2];
      #pragma unroll
      for (int g=0;g<2;++g)
        ap[g] = *(const s16x8*)&Pw[(g*16+(l&15))*72 + ks*32 + ((l>>4)*8)];
      #pragma unroll
      for (int nf=0;nf<4;++nf) {
        int row = nf*16 + (l&15);
        s16x8 bv = *(const s16x8*)&Vts[bi][row*64 + (((ks*4 + (l>>4)) ^ (l&7))*8)];
        #pragma unroll
        for (int g=0;g<2;++g)
          oacc[g][nf] = mfma16(ap[g], bv, oacc[g][nf]);
      }
    }
    __builtin_amdgcn_s_setprio(0);
  };

  // main loop: double-buffered, one barrier per chunk
  stage(0, 0);
  __syncthreads();
  for (int c=0;c<nch;++c) {
    if (c+1 < nch) stage(c+1, (c+1)&1);
    compute(c, c&1);
    __syncthreads();
  }
  // exact all-masked fallback: fully-padded rows must softmax uniformly over
  // ALL 1024 keys like the reference -> run the causally-dead chunks too.
  int dead = 0;
  #pragma unroll
  for (int g=0;g<2;++g)
    #pragma unroll
    for (int r=0;r<4;++r) dead |= (mrun[g][r] < -5e9f) ? 1 : 0;
  if (__syncthreads_or(dead)) {
    for (int c=nch;c<16;++c) {
      stage(c, c&1);
      __syncthreads();
      compute(c, c&1);
      __syncthreads();
    }
  }
  #pragma unroll
  for (int g=0;g<2;++g)
    #pragma unroll
    for (int nf=0;nf<4;++nf)
      #pragma unroll
      for (int r=0;r<4;++r) {
        int srow = r0 + g*16 + ((l>>4)<<2) + r;
        float o = oacc[g][nf][r] / lrun[g][r];
        outp[((size_t)bb*SS + srow)*DD + h*DHH + nf*16 + (l&15)] = f2b(o);
      }
}

// -------------------- driver --------------------
extern "C" void kernel_launch(void* const* d_in, const int* in_sizes, int n_in,
                              void* d_out, int out_size, void* d_ws, size_t ws_size,
                              hipStream_t stream) {
  const float* x    = (const float*)d_in[0];
  const int*   pad  = (const int*)d_in[1];   // bool mask as int32 on device
  const float* ln1g = (const float*)d_in[2];
  const float* ln1b = (const float*)d_in[3];
  const float* wq   = (const float*)d_in[4];
  const float* bq   = (const float*)d_in[5];
  const float* wkv  = (const float*)d_in[6];
  const float* bkv  = (const float*)d_in[7];
  const float* ln2g = (const float*)d_in[8];
  const float* ln2b = (const float*)d_in[9];
  const float* w1   = (const float*)d_in[10];
  const float* b1   = (const float*)d_in[11];
  const float* w2   = (const float*)d_in[12];
  const float* b2   = (const float*)d_in[13];

  char* ws = (char*)d_ws;
  const size_t MB = 1024*1024;
  short* ln1x = (short*)(ws + 0);        // 16MB, dead after KV gemm
  short* qb   = (short*)(ws + 16*MB);    // 16MB, dead after attn
  short* kpan = (short*)(ws + 32*MB);    //  8MB, dead after attn
  short* vtp  = (short*)(ws + 40*MB);    //  8MB, dead after attn
  u64*   pmar = (u64*)  (ws + 48*MB);    //  512B (in gap, free during attn)
  short* h1   = (short*)(ws + 0);        // 64MB, reuses [0,64MB) after attn
  short* outb = (short*)(ws + 64*MB);    // 16MB attn out
  short* hb   = (short*)(ws + 80*MB);    // 16MB ln2 out
  short* wqT  = (short*)(ws + 96*MB);    //  2MB
  short* wkvT = (short*)(ws + 98*MB);    //  4MB
  short* w1T  = (short*)(ws + 102*MB);   //  8MB
  short* w2T  = (short*)(ws + 110*MB);   //  8MB  (total 118MB)

  pad_bitmask<<<1,64,0,stream>>>(pad, pmar);
  transpose_cast<<<dim3(32,32),  256,0,stream>>>(wq,  wqT,  1024, 1024);
  transpose_cast<<<dim3(64,32),  256,0,stream>>>(wkv, wkvT, 1024, 2048);
  transpose_cast<<<dim3(128,32), 256,0,stream>>>(w1,  w1T,  1024, 4096);
  transpose_cast<<<dim3(32,128), 256,0,stream>>>(w2,  w2T,  4096, 1024);
  ln_kernel<0><<<MM,256,0,stream>>>(x, ln1g, ln1b, ln1x);
  gemm_bt<0><<<dim3(8,64), 256,0,stream>>>(ln1x, wqT,  bq,  qb,   nullptr, nullptr, 1024, 1024);
  gemm_bt<1><<<dim3(16,32),256,0,stream>>>(ln1x, wkvT, bkv, kpan, vtp,     nullptr, 2048, 1024);
  attn_kernel<<<dim3(16,16,4),256,0,stream>>>(qb, kpan, vtp, pmar, outb);
  ln_kernel<1><<<MM,256,0,stream>>>(outb, ln2g, ln2b, hb);
  gemm_bt<2><<<dim3(32,64),256,0,stream>>>(hb, w1T, b1, h1,    nullptr, nullptr, 4096, 1024);
  gemm_bt<3><<<dim3(8,64), 256,0,stream>>>(h1, w2T, b2, d_out, nullptr, x,       1024, 4096);
}